// Round 3
// baseline (111.982 us; speedup 1.0000x reference)
//
#include <hip/hip_runtime.h>

// RoPE on x:(4,32,4096,128) fp32, interleaved-pair convention.
// Thread owns a fixed (s, j) cell of the 4096 x 32 (seq, float4-in-row) plane,
// computes its sin/cos ONCE, then iterates over the b*h=128 slices that reuse
// the same angles. 524288 threads = 4 slices; 32 iterations each, all
// perfectly coalesced (lanes consecutive in pos, 131072 % 64 == 0).
// Memory-bound: 512 MiB traffic -> target ~85us @ copy ceiling.

__global__ void ROPE_23476291240446_kernel(const float4* __restrict__ x,
                                           float4* __restrict__ out) {
    const float C = -0.207620505929682f;     // -log2(10000)/64
    const float R = 0.865964323360110f;      // exp2(C): freq ratio, adjacent i

    int idx   = blockIdx.x * blockDim.x + threadIdx.x;  // [0, 524288)
    int pos   = idx & 131071;                // (s,j) cell: 131072 = 4096*32
    int slice = idx >> 17;                   // 0..3 -> starting bh
    int j = pos & 31;                        // float4 index within d-row
    int s = pos >> 5;                        // sequence position

    // One-time trig for this thread's (s, j): pairs i0=2j, i1=2j+1.
    float f0 = exp2f((float)(2 * j) * C);    // native v_exp_f32
    float f1 = f0 * R;
    float pf = (float)s;
    float s0, c0, s1, c1;
    __sincosf(pf * f0, &s0, &c0);
    __sincosf(pf * f1, &s1, &c1);

    // bh-slices are 131072 float4 (= 2 MiB) apart.
    #pragma unroll 4
    for (int bh = slice; bh < 128; bh += 4) {
        long v = (long)bh * 131072 + pos;
        float4 xv = x[v];
        float4 o;
        o.x = xv.x * c0 - xv.y * s0;
        o.y = xv.x * s0 + xv.y * c0;
        o.z = xv.z * c1 - xv.w * s1;
        o.w = xv.z * s1 + xv.w * c1;
        out[v] = o;
    }
}

extern "C" void kernel_launch(void* const* d_in, const int* in_sizes, int n_in,
                              void* d_out, int out_size, void* d_ws, size_t ws_size,
                              hipStream_t stream) {
    const float* x = (const float*)d_in[0];
    float* out = (float*)d_out;

    const int block = 256;
    const int grid = 2048;                   // 524288 threads = 32 waves/CU exactly
    ROPE_23476291240446_kernel<<<grid, block, 0, stream>>>(
        (const float4*)x, (float4*)out);
}

// Round 4
// 85.484 us; speedup vs baseline: 1.3100x; 1.3100x over previous
//
#include <hip/hip_runtime.h>

// RoPE on x:(4,32,4096,128) fp32, interleaved-pair convention.
// One float4 (= 2 rotation pairs) per thread; 65536 blocks x 256 threads.
// Maximal MLP: every load issues at wave start, trig overlaps load latency.
// Nontemporal load+store: both streams are touch-once (512 MiB total vs
// 256 MiB L3) -- bypass cache allocation to avoid thrash / write-allocate.
// Floor: 536.9 MB @ 6.29 TB/s (m13 copy ceiling) = ~85 us.

typedef float v4f __attribute__((ext_vector_type(4)));

__global__ void ROPE_23476291240446_kernel(const v4f* __restrict__ x,
                                           v4f* __restrict__ out) {
    const float C = -0.207620505929682f;     // -log2(10000)/64
    const float R = 0.865964323360110f;      // exp2(C): freq ratio, adjacent i

    int v = blockIdx.x * blockDim.x + threadIdx.x;   // [0, 16777216)
    int j = v & 31;                          // float4 index within d=128 row
    int s = (v >> 5) & 4095;                 // sequence position

    v4f xv = __builtin_nontemporal_load(&x[v]);   // issues before trig resolves

    float f0 = exp2f((float)(2 * j) * C);    // native v_exp_f32
    float f1 = f0 * R;
    float pf = (float)s;
    float s0, c0, s1, c1;
    __sincosf(pf * f0, &s0, &c0);
    __sincosf(pf * f1, &s1, &c1);

    v4f o;
    o.x = xv.x * c0 - xv.y * s0;
    o.y = xv.x * s0 + xv.y * c0;
    o.z = xv.z * c1 - xv.w * s1;
    o.w = xv.z * s1 + xv.w * c1;
    __builtin_nontemporal_store(o, &out[v]);
}

extern "C" void kernel_launch(void* const* d_in, const int* in_sizes, int n_in,
                              void* d_out, int out_size, void* d_ws, size_t ws_size,
                              hipStream_t stream) {
    const v4f* x = (const v4f*)d_in[0];
    v4f* out = (v4f*)d_out;

    int n4 = in_sizes[0] / 4;                // 16,777,216 float4s
    const int block = 256;
    int grid = n4 / block;                   // 65536 blocks, exact
    ROPE_23476291240446_kernel<<<grid, block, 0, stream>>>(x, out);
}